// Round 17
// baseline (112.850 us; speedup 1.0000x reference)
//
#include <hip/hip_runtime.h>
#include <hip/hip_bf16.h>

// Modulated conv2d (StyleGAN2) on MI355X.
// out[b,o] = rsig[b,o] * conv(s[b,:]*x[b,:], W*SCALE)   (shared weights)
// rsig[b,o] = 1/sqrt(sum_i s[b,i]^2 * wsq[o,i] + 1e-8)
// Conv as implicit GEMM: D[o][p] = sum_k Wb[o][k] * Xcl[p][k].
//
// R17 = R16 (best composition: R6 conv body + R10 tail) with ONE change:
// mfma_f32_16x16x32 -> mfma_f32_32x32x16 (8.07 vs ~9.7 cyc per 32KFLOP,
// 17% cheaper MFMA pipe; instruction count halves). LDS layout, staging,
// XOR swizzle, z-split, tail: byte-identical to R16. Bank audit: operand
// read row=base+(lane&31), chunk=(2ks+(lane>>5))^(row&7): each quarter-wave
// = 16 consecutive rows -> 8 chunk-groups x 2 lanes = conflict-free (m136).
// C/D map (guide-verified m74/m101): col=lane&31,
// row=(reg&3)+8*(reg>>2)+4*(lane>>5).

typedef __attribute__((ext_vector_type(4))) float f32x4;
typedef __attribute__((ext_vector_type(16))) float f32x16;
typedef __attribute__((ext_vector_type(8))) short bf16x8;

#define NB    16
#define CIN   512
#define COUT  512
#define KTOT  4608           // CIN * 9
#define NPIX  (NB * 32 * 32) // 16384
#define KTPZ  36             // K64-tiles per z-half

__device__ __forceinline__ void gload_lds16(const void* g, void* l) {
  __builtin_amdgcn_global_load_lds(
      (__attribute__((address_space(1))) void*)(g),
      (__attribute__((address_space(3))) void*)(l), 16, 0, 0);
}

__device__ __forceinline__ float bf16bits_to_f32(short v) {
  return __uint_as_float(((unsigned)(unsigned short)v) << 16);
}

// ---- kernel 1: pack weights (bf16, [o][tap*512+ci]) + wsq ----
__global__ __launch_bounds__(256) void pack_w_kernel(
    const float* __restrict__ w, __hip_bfloat16* __restrict__ wB,
    float* __restrict__ wsq) {
  const int idx = blockIdx.x * 256 + threadIdx.x;   // = o*512 + ci
  const int o = idx >> 9, ci = idx & 511;
  const float* wp = w + (size_t)idx * 9;
  const float WSCALE = 0.014731391274719739f;       // 1/sqrt(512*9)
  float sum = 0.f;
#pragma unroll
  for (int t = 0; t < 9; ++t) {
    float v = wp[t] * WSCALE;
    sum += v * v;
    wB[(size_t)o * KTOT + t * 512 + ci] = __float2bfloat16(v);
  }
  wsq[idx] = sum;
}

// ---- kernel 2: rsig[b][o], one wave per (b,o) ----
__global__ __launch_bounds__(256) void calc_rsig_kernel(
    const float* __restrict__ s, const float* __restrict__ wsq,
    float* __restrict__ rsig) {
  const int wid = blockIdx.x * 4 + (threadIdx.x >> 6); // b*512 + o
  const int lane = threadIdx.x & 63;
  const int b = wid >> 9, o = wid & 511;
  const float* sp = s + b * 512;
  const float* wp = wsq + o * 512;
  float sum = 0.f;
#pragma unroll
  for (int i = 0; i < 8; ++i) {
    float sv = sp[lane + i * 64];
    sum += sv * sv * wp[lane + i * 64];
  }
#pragma unroll
  for (int off = 32; off > 0; off >>= 1) sum += __shfl_down(sum, off, 64);
  if (lane == 0) rsig[wid] = 1.0f / sqrtf(sum + 1e-8f);
}

// ---- kernel 3: modulate + NCHW -> padded channels-last bf16 ----
__global__ __launch_bounds__(256) void modulate_kernel(
    const float* __restrict__ x, const float* __restrict__ s,
    __hip_bfloat16* __restrict__ xpad) {
  const int by = blockIdx.x;            // b*32 + y
  const int b = by >> 5, y = by & 31;
  __shared__ __attribute__((aligned(16))) __hip_bfloat16 tile[32][72];
  const int tid = threadIdx.x;
  const int xc = tid & 31;
  const int cr0 = tid >> 5;
  const float* xrow = x + ((size_t)b * 512 * 32 + y) * 32;
  const float* sb = s + b * 512;
  __hip_bfloat16* orow = xpad + (size_t)((b * 34 + y + 1) * 34) * 512;

  for (int ci0 = 0; ci0 < 512; ci0 += 64) {
#pragma unroll
    for (int r = 0; r < 8; ++r) {
      const int cir = r * 8 + cr0;
      const int ci = ci0 + cir;
      float v = xrow[(size_t)ci * 1024 + xc] * sb[ci];
      tile[xc][cir] = __float2bfloat16(v);
    }
    __syncthreads();
    const int xcw = tid >> 3, vec = tid & 7;
    bf16x8 v = *(const bf16x8*)&tile[xcw][vec * 8];
    *(bf16x8*)(orow + (size_t)(xcw + 1) * 512 + ci0 + vec * 8) = v;
    __syncthreads();
  }
}

// ---- kernel 3b: zero only the halo of xpad ----
__global__ __launch_bounds__(256) void halo_zero_kernel(
    __hip_bfloat16* __restrict__ xpad) {
  const int sb = blockIdx.x;           // b*132 + site
  const int b = sb / 132, s = sb - b * 132;
  int y, x;
  if (s < 34)       { y = 0;        x = s; }
  else if (s < 68)  { y = 33;       x = s - 34; }
  else if (s < 100) { y = s - 67;   x = 0; }
  else              { y = s - 99;   x = 33; }
  unsigned* p = (unsigned*)(xpad + (size_t)((b * 34 + y) * 34 + x) * 512);
  p[threadIdx.x] = 0u;   // 256 x 4B = 512 bf16
}

// ---- kernel 4: implicit-GEMM conv (R6 body, 32x32x16 MFMA), z-split x2 ----
// Block: 128 cout x 256 pix x K2304 (36 K64-tiles). 256 thr, 4 waves 2Mx2N,
// per-wave 64x128 (acc f32x16[2][4]). LDS: A[128][64] 16KB + B[256][64]
// 32KB, single-buffered, row-major 128B rows, XOR chunk swizzle
// chunk^=(row&7) on staging source + ds_read (rule 21; 0 conflicts R1-R16).
__global__ __launch_bounds__(256, 2) void conv_gemm_kernel(
    const __hip_bfloat16* __restrict__ wB,    // [512][4608]
    const __hip_bfloat16* __restrict__ xpad,  // [16][34][34][512]
    const float* __restrict__ rsig,           // [16][512]
    float* __restrict__ out,                  // f32 out (fallback, z=0)
    __hip_bfloat16* __restrict__ p0,          // bf16 partial z=0 (or null)
    __hip_bfloat16* __restrict__ p1) {        // bf16 partial z=1
  __shared__ __attribute__((aligned(16))) __hip_bfloat16 ldsA[128 * 64];
  __shared__ __attribute__((aligned(16))) __hip_bfloat16 ldsB[256 * 64];

  const int tid = threadIdx.x;
  const int wv = tid >> 6, lane = tid & 63, l31 = lane & 31;
  const int lhi = lane >> 5;         // 0/1: k-half of the lane
  const int bo0 = blockIdx.y << 7;   // cout block (128)
  const int bp0 = blockIdx.x << 8;   // pixel block (256; 256 | 1024 per image)
  const int z = blockIdx.z;          // K-half
  const int bimg = blockIdx.x >> 2;
  const int wr = wv >> 1, wc = wv & 1;

  // Staging source offsets (pre-swizzled chunk within row; rule 21).
  int gA[4];   // + ktg*64 per tile
#pragma unroll
  for (int r = 0; r < 4; ++r) {
    const int c = r * 256 + tid, row = c >> 3, sc = (c & 7) ^ (row & 7);
    gA[r] = (bo0 + row) * KTOT + sc * 8;
  }
  int gB[8];   // + tapoff*512 + ci0 per tile
#pragma unroll
  for (int r = 0; r < 8; ++r) {
    const int c = r * 256 + tid, row = c >> 3, sc = (c & 7) ^ (row & 7);
    const int p = bp0 + row, b = p >> 10, rem = p & 1023, y = rem >> 5,
              xx = rem & 31;
    gB[r] = ((b * 34 + y) * 34 + xx) * 512 + sc * 8;
  }

  f32x16 acc[2][4];
#pragma unroll
  for (int mi = 0; mi < 2; ++mi)
#pragma unroll
    for (int ni = 0; ni < 4; ++ni)
#pragma unroll
      for (int e = 0; e < 16; ++e) acc[mi][ni][e] = 0.f;

#pragma unroll 1
  for (int kt = 0; kt < KTPZ; ++kt) {
    const int ktg = z * KTPZ + kt;
    const int tap = ktg >> 3;
    const int xoff = (tap + 31 * (tap / 3)) * 512 + ((ktg & 7) << 6);
    // ---- stage tile (12 x 16B per thread) ----
#pragma unroll
    for (int r = 0; r < 4; ++r)
      gload_lds16(wB + (size_t)(gA[r] + (ktg << 6)),
                  (char*)ldsA + (r * 256 + tid) * 16);
#pragma unroll
    for (int r = 0; r < 8; ++r)
      gload_lds16(xpad + (size_t)(gB[r] + xoff),
                  (char*)ldsB + (r * 256 + tid) * 16);
    __syncthreads();   // drains vmcnt -> staged data visible

    // ---- 4 k16-steps x (2 mi x 4 ni) 32x32x16 MFMA ----
#pragma unroll
    for (int ks = 0; ks < 4; ++ks) {
      const int kchunk = (ks << 1) | lhi;   // 16B chunk 0..7 within row
      bf16x8 af[2], bv[4];
#pragma unroll
      for (int mi = 0; mi < 2; ++mi) {
        const int row = (wr << 6) + (mi << 5) + l31;
        af[mi] = *(const bf16x8*)((const char*)ldsA + row * 128 +
                                  ((kchunk ^ (row & 7)) << 4));
      }
#pragma unroll
      for (int ni = 0; ni < 4; ++ni) {
        const int row = (wc << 7) + (ni << 5) + l31;
        bv[ni] = *(const bf16x8*)((const char*)ldsB + row * 128 +
                                  ((kchunk ^ (row & 7)) << 4));
      }
#pragma unroll
      for (int mi = 0; mi < 2; ++mi)
#pragma unroll
        for (int ni = 0; ni < 4; ++ni)
          acc[mi][ni] = __builtin_amdgcn_mfma_f32_32x32x16_bf16(
              af[mi], bv[ni], acc[mi][ni], 0, 0, 0);
    }
    __syncthreads();   // all reads done before next stage overwrites
  }

  // Epilogue: scale by rsig -> bf16 partial pz (f32 out if p0==null && z==0).
  // C/D (32x32, m74/m101): col=lane&31, row=(reg&3)+8*(reg>>2)+4*(lane>>5).
  __hip_bfloat16* pz = z ? p1 : p0;
  const bool f32path = (p0 == nullptr) && (z == 0);
#pragma unroll
  for (int mi = 0; mi < 2; ++mi) {
    const int obase = bo0 + (wr << 6) + (mi << 5);
#pragma unroll
    for (int q = 0; q < 4; ++q) {
      const int o4 = obase + (q << 3) + (lhi << 2);   // 4 consecutive o
      const f32x4 rs = *(const f32x4*)(rsig + (bimg << 9) + o4);
#pragma unroll
      for (int ni = 0; ni < 4; ++ni) {
        const int p = bp0 + (wc << 7) + (ni << 5) + l31;
        const int prem = p & 1023;
#pragma unroll
        for (int j = 0; j < 4; ++j) {
          const float v = acc[mi][ni][(q << 2) + j] * rs[j];
          const size_t oidx = ((size_t)((bimg << 9) + o4 + j)) * 1024 + prem;
          if (f32path) out[oidx] = v;
          else pz[oidx] = __float2bfloat16(v);
        }
      }
    }
  }
}

// ---- kernel 5a: merge out = p0 + p1 ----
__global__ __launch_bounds__(256) void merge2_kernel(
    float* __restrict__ out, const __hip_bfloat16* __restrict__ p0,
    const __hip_bfloat16* __restrict__ p1) {
  const size_t i = (size_t)blockIdx.x * 256 + threadIdx.x;
  const bf16x8 a = ((const bf16x8*)p0)[i];
  const bf16x8 b = ((const bf16x8*)p1)[i];
  f32x4 o0, o1;
#pragma unroll
  for (int j = 0; j < 4; ++j) {
    o0[j] = bf16bits_to_f32(a[j]) + bf16bits_to_f32(b[j]);
    o1[j] = bf16bits_to_f32(a[4 + j]) + bf16bits_to_f32(b[4 + j]);
  }
  ((f32x4*)out)[2 * i] = o0;
  ((f32x4*)out)[2 * i + 1] = o1;
}

// ---- kernel 5b: fallback merge out += p1 ----
__global__ __launch_bounds__(256) void merge1_kernel(
    float* __restrict__ out, const __hip_bfloat16* __restrict__ p1) {
  const size_t i = (size_t)blockIdx.x * 256 + threadIdx.x;
  f32x4* o4 = (f32x4*)out + 2 * i;
  f32x4 a = o4[0], b = o4[1];
  const bf16x8 pv = ((const bf16x8*)p1)[i];
#pragma unroll
  for (int j = 0; j < 4; ++j) {
    a[j] += bf16bits_to_f32(pv[j]);
    b[j] += bf16bits_to_f32(pv[4 + j]);
  }
  o4[0] = a;
  o4[1] = b;
}

extern "C" void kernel_launch(void* const* d_in, const int* in_sizes, int n_in,
                              void* d_out, int out_size, void* d_ws,
                              size_t ws_size, hipStream_t stream) {
  const float* x = (const float*)d_in[0];   // [16,512,32,32]
  const float* s = (const float*)d_in[1];   // [16,512]
  const float* w = (const float*)d_in[2];   // [512,512,3,3]
  float* out = (float*)d_out;               // [16,512,32,32] f32

  char* ws = (char*)d_ws;
  const size_t xpad_bytes = (size_t)NB * 34 * 34 * 512 * 2;  // 18,939,904
  const size_t wB_bytes = (size_t)COUT * KTOT * 2;           //  4,718,592
  const size_t wsq_bytes = (size_t)COUT * CIN * 4;           //  1,048,576
  const size_t rsig_bytes = (size_t)NB * COUT * 4;           //     32,768
  const size_t part_bytes = (size_t)NPIX * COUT * 2;         // 16,777,216
  const size_t base_bytes = xpad_bytes + wB_bytes + wsq_bytes + rsig_bytes;
  __hip_bfloat16* xpad = (__hip_bfloat16*)ws;
  __hip_bfloat16* wB = (__hip_bfloat16*)(ws + xpad_bytes);
  float* wsq = (float*)(ws + xpad_bytes + wB_bytes);
  float* rsig = (float*)(ws + xpad_bytes + wB_bytes + wsq_bytes);
  __hip_bfloat16* pa = (__hip_bfloat16*)(ws + base_bytes);
  __hip_bfloat16* pb = (__hip_bfloat16*)(ws + base_bytes + part_bytes);
  const bool fits2 = ws_size >= base_bytes + 2 * part_bytes;

  halo_zero_kernel<<<NB * 132, 256, 0, stream>>>(xpad);
  pack_w_kernel<<<(COUT * CIN) / 256, 256, 0, stream>>>(w, wB, wsq);
  modulate_kernel<<<NB * 32, 256, 0, stream>>>(x, s, xpad);
  calc_rsig_kernel<<<(NB * COUT) / 4, 256, 0, stream>>>(s, wsq, rsig);

  const int mblocks = (NPIX * COUT / 8) / 256;   // 4096
  if (fits2) {
    conv_gemm_kernel<<<dim3(NPIX / 256, COUT / 128, 2), 256, 0, stream>>>(
        wB, xpad, rsig, out, pa, pb);
    merge2_kernel<<<mblocks, 256, 0, stream>>>(out, pa, pb);
  } else {
    conv_gemm_kernel<<<dim3(NPIX / 256, COUT / 128, 2), 256, 0, stream>>>(
        wB, xpad, rsig, out, nullptr, pa);
    merge1_kernel<<<mblocks, 256, 0, stream>>>(out, pa);
  }
}

// Round 18
// 103.214 us; speedup vs baseline: 1.0934x; 1.0934x over previous
//
#include <hip/hip_runtime.h>
#include <hip/hip_bf16.h>

// Modulated conv2d (StyleGAN2) on MI355X — FINAL (R18 = R16 frozen).
// out[b,o] = rsig[b,o] * conv(s[b,:]*x[b,:], W*SCALE)   (shared weights)
// rsig[b,o] = 1/sqrt(sum_i s[b,i]^2 * wsq[o,i] + 1e-8)
// Conv as implicit GEMM: D[o][p] = sum_k Wb[o][k] * Xcl[p][k].
//
// Best verified composition over 17 rounds (103.2us total; conv 74.1us,
// MfmaUtil 45%, 0 bank conflicts, no spill):
//  - conv = R6 body: BK=64, single-buffer 48KB LDS, plain 2x __syncthreads
//    per K-tile, 256 thr / 4 waves 2Mx2N, per-wave 64x128, 16x16x32 MFMA,
//    z-split x2 -> 512 blocks = 2 independent blocks/CU. Row-major 128B LDS
//    rows + XOR chunk swizzle (rule 21), 128B-contiguous gload_lds staging.
//  - tail = R10: halo-only zero, bf16 partials both z-halves, merge2.
// Refuted alternatives (measured): pipelined schedules R2/R4/R7/R11/R14/R15
// (stage/barrier machinery dominates; R15 proved conflicts-0 != faster),
// A-in-registers R3/R12 (L2 refetch / VGPR spill), fragment-major staging
// R9 (scattered DMA), 3 blk/CU R13, 32x32x16 shape R17 (bank conflicts).

typedef __attribute__((ext_vector_type(4))) float f32x4;
typedef __attribute__((ext_vector_type(8))) short bf16x8;

#define NB    16
#define CIN   512
#define COUT  512
#define KTOT  4608           // CIN * 9
#define NPIX  (NB * 32 * 32) // 16384
#define KTPZ  36             // K64-tiles per z-half

__device__ __forceinline__ void gload_lds16(const void* g, void* l) {
  __builtin_amdgcn_global_load_lds(
      (__attribute__((address_space(1))) void*)(g),
      (__attribute__((address_space(3))) void*)(l), 16, 0, 0);
}

__device__ __forceinline__ float bf16bits_to_f32(short v) {
  return __uint_as_float(((unsigned)(unsigned short)v) << 16);
}

// ---- kernel 1: pack weights (bf16, [o][tap*512+ci]) + wsq ----
__global__ __launch_bounds__(256) void pack_w_kernel(
    const float* __restrict__ w, __hip_bfloat16* __restrict__ wB,
    float* __restrict__ wsq) {
  const int idx = blockIdx.x * 256 + threadIdx.x;   // = o*512 + ci
  const int o = idx >> 9, ci = idx & 511;
  const float* wp = w + (size_t)idx * 9;
  const float WSCALE = 0.014731391274719739f;       // 1/sqrt(512*9)
  float sum = 0.f;
#pragma unroll
  for (int t = 0; t < 9; ++t) {
    float v = wp[t] * WSCALE;
    sum += v * v;
    wB[(size_t)o * KTOT + t * 512 + ci] = __float2bfloat16(v);
  }
  wsq[idx] = sum;
}

// ---- kernel 2: rsig[b][o], one wave per (b,o) ----
__global__ __launch_bounds__(256) void calc_rsig_kernel(
    const float* __restrict__ s, const float* __restrict__ wsq,
    float* __restrict__ rsig) {
  const int wid = blockIdx.x * 4 + (threadIdx.x >> 6); // b*512 + o
  const int lane = threadIdx.x & 63;
  const int b = wid >> 9, o = wid & 511;
  const float* sp = s + b * 512;
  const float* wp = wsq + o * 512;
  float sum = 0.f;
#pragma unroll
  for (int i = 0; i < 8; ++i) {
    float sv = sp[lane + i * 64];
    sum += sv * sv * wp[lane + i * 64];
  }
#pragma unroll
  for (int off = 32; off > 0; off >>= 1) sum += __shfl_down(sum, off, 64);
  if (lane == 0) rsig[wid] = 1.0f / sqrtf(sum + 1e-8f);
}

// ---- kernel 3: modulate + NCHW -> padded channels-last bf16 ----
__global__ __launch_bounds__(256) void modulate_kernel(
    const float* __restrict__ x, const float* __restrict__ s,
    __hip_bfloat16* __restrict__ xpad) {
  const int by = blockIdx.x;            // b*32 + y
  const int b = by >> 5, y = by & 31;
  __shared__ __attribute__((aligned(16))) __hip_bfloat16 tile[32][72];
  const int tid = threadIdx.x;
  const int xc = tid & 31;
  const int cr0 = tid >> 5;
  const float* xrow = x + ((size_t)b * 512 * 32 + y) * 32;
  const float* sb = s + b * 512;
  __hip_bfloat16* orow = xpad + (size_t)((b * 34 + y + 1) * 34) * 512;

  for (int ci0 = 0; ci0 < 512; ci0 += 64) {
#pragma unroll
    for (int r = 0; r < 8; ++r) {
      const int cir = r * 8 + cr0;
      const int ci = ci0 + cir;
      float v = xrow[(size_t)ci * 1024 + xc] * sb[ci];
      tile[xc][cir] = __float2bfloat16(v);
    }
    __syncthreads();
    const int xcw = tid >> 3, vec = tid & 7;
    bf16x8 v = *(const bf16x8*)&tile[xcw][vec * 8];
    *(bf16x8*)(orow + (size_t)(xcw + 1) * 512 + ci0 + vec * 8) = v;
    __syncthreads();
  }
}

// ---- kernel 3b: zero only the halo of xpad ----
__global__ __launch_bounds__(256) void halo_zero_kernel(
    __hip_bfloat16* __restrict__ xpad) {
  const int sb = blockIdx.x;           // b*132 + site
  const int b = sb / 132, s = sb - b * 132;
  int y, x;
  if (s < 34)       { y = 0;        x = s; }
  else if (s < 68)  { y = 33;       x = s - 34; }
  else if (s < 100) { y = s - 67;   x = 0; }
  else              { y = s - 99;   x = 33; }
  unsigned* p = (unsigned*)(xpad + (size_t)((b * 34 + y) * 34 + x) * 512);
  p[threadIdx.x] = 0u;   // 256 x 4B = 512 bf16
}

// ---- kernel 4: implicit-GEMM conv (R6 body), z-split x2 ----
// Block: 128 cout x 256 pix x K2304 (36 K64-tiles). 256 thr, 4 waves 2Mx2N,
// per-wave 64x128 (acc 4x8). LDS: A[128][64] 16KB + B[256][64] 32KB,
// single-buffered, row-major 128B rows, XOR swizzle byte^=((row&7)<<4) on
// staging source chunk + ds_read (rule 21; 0 conflicts measured R1-R16).
__global__ __launch_bounds__(256, 2) void conv_gemm_kernel(
    const __hip_bfloat16* __restrict__ wB,    // [512][4608]
    const __hip_bfloat16* __restrict__ xpad,  // [16][34][34][512]
    const float* __restrict__ rsig,           // [16][512]
    float* __restrict__ out,                  // f32 out (fallback, z=0)
    __hip_bfloat16* __restrict__ p0,          // bf16 partial z=0 (or null)
    __hip_bfloat16* __restrict__ p1) {        // bf16 partial z=1
  __shared__ __attribute__((aligned(16))) __hip_bfloat16 ldsA[128 * 64];
  __shared__ __attribute__((aligned(16))) __hip_bfloat16 ldsB[256 * 64];

  const int tid = threadIdx.x;
  const int wv = tid >> 6, lane = tid & 63, l15 = lane & 15;
  const int bo0 = blockIdx.y << 7;   // cout block (128)
  const int bp0 = blockIdx.x << 8;   // pixel block (256; 256 | 1024 per image)
  const int z = blockIdx.z;          // K-half
  const int bimg = blockIdx.x >> 2;
  const int wr = wv >> 1, wc = wv & 1;

  // Staging source offsets (pre-swizzled chunk within row; rule 21).
  int gA[4];   // + ktg*64 per tile
#pragma unroll
  for (int r = 0; r < 4; ++r) {
    const int c = r * 256 + tid, row = c >> 3, sc = (c & 7) ^ (row & 7);
    gA[r] = (bo0 + row) * KTOT + sc * 8;
  }
  int gB[8];   // + tapoff*512 + ci0 per tile
#pragma unroll
  for (int r = 0; r < 8; ++r) {
    const int c = r * 256 + tid, row = c >> 3, sc = (c & 7) ^ (row & 7);
    const int p = bp0 + row, b = p >> 10, rem = p & 1023, y = rem >> 5,
              xx = rem & 31;
    gB[r] = ((b * 34 + y) * 34 + xx) * 512 + sc * 8;
  }

  f32x4 acc[4][8];
#pragma unroll
  for (int mi = 0; mi < 4; ++mi)
#pragma unroll
    for (int ni = 0; ni < 8; ++ni) acc[mi][ni] = f32x4{0.f, 0.f, 0.f, 0.f};

  const int kb0 = (lane >> 4) << 4;   // byte base of this lane's k-slot

#pragma unroll 1
  for (int kt = 0; kt < KTPZ; ++kt) {
    const int ktg = z * KTPZ + kt;
    const int tap = ktg >> 3;
    const int xoff = (tap + 31 * (tap / 3)) * 512 + ((ktg & 7) << 6);
    // ---- stage tile (12 x 16B per thread) ----
#pragma unroll
    for (int r = 0; r < 4; ++r)
      gload_lds16(wB + (size_t)(gA[r] + (ktg << 6)),
                  (char*)ldsA + (r * 256 + tid) * 16);
#pragma unroll
    for (int r = 0; r < 8; ++r)
      gload_lds16(xpad + (size_t)(gB[r] + xoff),
                  (char*)ldsB + (r * 256 + tid) * 16);
    __syncthreads();   // drains vmcnt -> staged data visible

    bf16x8 af[4][2];
#pragma unroll
    for (int mi = 0; mi < 4; ++mi) {
      const int row = (wr << 6) + (mi << 4) + l15;
      const int swz = (row & 7) << 4;
      af[mi][0] = *(const bf16x8*)((const char*)ldsA + row * 128 + (kb0 ^ swz));
      af[mi][1] = *(const bf16x8*)((const char*)ldsA + row * 128 + ((64 | kb0) ^ swz));
    }
    {
      bf16x8 bv[8];
#pragma unroll
      for (int ni = 0; ni < 8; ++ni) {
        const int row = (wc << 7) + (ni << 4) + l15;
        bv[ni] = *(const bf16x8*)((const char*)ldsB + row * 128 +
                                  (kb0 ^ ((row & 7) << 4)));
      }
#pragma unroll
      for (int mi = 0; mi < 4; ++mi)
#pragma unroll
        for (int ni = 0; ni < 8; ++ni)
          acc[mi][ni] = __builtin_amdgcn_mfma_f32_16x16x32_bf16(
              af[mi][0], bv[ni], acc[mi][ni], 0, 0, 0);
    }
    {
      bf16x8 bv[8];
#pragma unroll
      for (int ni = 0; ni < 8; ++ni) {
        const int row = (wc << 7) + (ni << 4) + l15;
        bv[ni] = *(const bf16x8*)((const char*)ldsB + row * 128 +
                                  ((64 | kb0) ^ ((row & 7) << 4)));
      }
#pragma unroll
      for (int mi = 0; mi < 4; ++mi)
#pragma unroll
        for (int ni = 0; ni < 8; ++ni)
          acc[mi][ni] = __builtin_amdgcn_mfma_f32_16x16x32_bf16(
              af[mi][1], bv[ni], acc[mi][ni], 0, 0, 0);
    }
    __syncthreads();   // all reads done before next stage overwrites
  }

  // Epilogue: scale by rsig -> bf16 partial pz (f32 out if p0==null && z==0).
  // C/D: col(=p)=lane&15, row(=o)=(lane>>4)*4+r
  __hip_bfloat16* pz = z ? p1 : p0;
  const bool f32path = (p0 == nullptr) && (z == 0);
#pragma unroll
  for (int mi = 0; mi < 4; ++mi) {
    const int o = bo0 + (wr << 6) + (mi << 4) + ((lane >> 4) << 2);
    const f32x4 rs = *(const f32x4*)(rsig + (bimg << 9) + o);
#pragma unroll
    for (int ni = 0; ni < 8; ++ni) {
      const int p = bp0 + (wc << 7) + (ni << 4) + l15;
      const int prem = p & 1023;
#pragma unroll
      for (int r = 0; r < 4; ++r) {
        const float v = acc[mi][ni][r] * rs[r];
        const size_t oidx = ((size_t)((bimg << 9) + o + r)) * 1024 + prem;
        if (f32path) out[oidx] = v;
        else pz[oidx] = __float2bfloat16(v);
      }
    }
  }
}

// ---- kernel 5a: merge out = p0 + p1 ----
__global__ __launch_bounds__(256) void merge2_kernel(
    float* __restrict__ out, const __hip_bfloat16* __restrict__ p0,
    const __hip_bfloat16* __restrict__ p1) {
  const size_t i = (size_t)blockIdx.x * 256 + threadIdx.x;
  const bf16x8 a = ((const bf16x8*)p0)[i];
  const bf16x8 b = ((const bf16x8*)p1)[i];
  f32x4 o0, o1;
#pragma unroll
  for (int j = 0; j < 4; ++j) {
    o0[j] = bf16bits_to_f32(a[j]) + bf16bits_to_f32(b[j]);
    o1[j] = bf16bits_to_f32(a[4 + j]) + bf16bits_to_f32(b[4 + j]);
  }
  ((f32x4*)out)[2 * i] = o0;
  ((f32x4*)out)[2 * i + 1] = o1;
}

// ---- kernel 5b: fallback merge out += p1 ----
__global__ __launch_bounds__(256) void merge1_kernel(
    float* __restrict__ out, const __hip_bfloat16* __restrict__ p1) {
  const size_t i = (size_t)blockIdx.x * 256 + threadIdx.x;
  f32x4* o4 = (f32x4*)out + 2 * i;
  f32x4 a = o4[0], b = o4[1];
  const bf16x8 pv = ((const bf16x8*)p1)[i];
#pragma unroll
  for (int j = 0; j < 4; ++j) {
    a[j] += bf16bits_to_f32(pv[j]);
    b[j] += bf16bits_to_f32(pv[4 + j]);
  }
  o4[0] = a;
  o4[1] = b;
}

extern "C" void kernel_launch(void* const* d_in, const int* in_sizes, int n_in,
                              void* d_out, int out_size, void* d_ws,
                              size_t ws_size, hipStream_t stream) {
  const float* x = (const float*)d_in[0];   // [16,512,32,32]
  const float* s = (const float*)d_in[1];   // [16,512]
  const float* w = (const float*)d_in[2];   // [512,512,3,3]
  float* out = (float*)d_out;               // [16,512,32,32] f32

  char* ws = (char*)d_ws;
  const size_t xpad_bytes = (size_t)NB * 34 * 34 * 512 * 2;  // 18,939,904
  const size_t wB_bytes = (size_t)COUT * KTOT * 2;           //  4,718,592
  const size_t wsq_bytes = (size_t)COUT * CIN * 4;           //  1,048,576
  const size_t rsig_bytes = (size_t)NB * COUT * 4;           //     32,768
  const size_t part_bytes = (size_t)NPIX * COUT * 2;         // 16,777,216
  const size_t base_bytes = xpad_bytes + wB_bytes + wsq_bytes + rsig_bytes;
  __hip_bfloat16* xpad = (__hip_bfloat16*)ws;
  __hip_bfloat16* wB = (__hip_bfloat16*)(ws + xpad_bytes);
  float* wsq = (float*)(ws + xpad_bytes + wB_bytes);
  float* rsig = (float*)(ws + xpad_bytes + wB_bytes + wsq_bytes);
  __hip_bfloat16* pa = (__hip_bfloat16*)(ws + base_bytes);
  __hip_bfloat16* pb = (__hip_bfloat16*)(ws + base_bytes + part_bytes);
  const bool fits2 = ws_size >= base_bytes + 2 * part_bytes;

  halo_zero_kernel<<<NB * 132, 256, 0, stream>>>(xpad);
  pack_w_kernel<<<(COUT * CIN) / 256, 256, 0, stream>>>(w, wB, wsq);
  modulate_kernel<<<NB * 32, 256, 0, stream>>>(x, s, xpad);
  calc_rsig_kernel<<<(NB * COUT) / 4, 256, 0, stream>>>(s, wsq, rsig);

  const int mblocks = (NPIX * COUT / 8) / 256;   // 4096
  if (fits2) {
    conv_gemm_kernel<<<dim3(NPIX / 256, COUT / 128, 2), 256, 0, stream>>>(
        wB, xpad, rsig, out, pa, pb);
    merge2_kernel<<<mblocks, 256, 0, stream>>>(out, pa, pb);
  } else {
    conv_gemm_kernel<<<dim3(NPIX / 256, COUT / 128, 2), 256, 0, stream>>>(
        wB, xpad, rsig, out, nullptr, pa);
    merge1_kernel<<<mblocks, 256, 0, stream>>>(out, pa);
  }
}